// Round 1
// baseline (855.007 us; speedup 1.0000x reference)
//
#include <hip/hip_runtime.h>
#include <math.h>

// Problem constants (from reference): N=50000 nodes, H=8 heads, DK=32.
#define HEADS 8
#define DKDIM 32
#define REC   (HEADS * DKDIM)   // 256 floats per node per tensor

__global__ void zero_kernel(float* __restrict__ out, int n) {
    int i = blockIdx.x * blockDim.x + threadIdx.x;
    int stride = gridDim.x * blockDim.x;
    for (; i < n; i += stride) out[i] = 0.0f;
}

// One 256-thread block per edge (grid-strided).
// tid -> (h = tid>>5, d = tid&31). Loads of k[src], q[dst], v[src] are
// fully coalesced (256 contiguous floats per node record).
__global__ __launch_bounds__(256) void edge_kernel(
    const float* __restrict__ q, const float* __restrict__ k,
    const float* __restrict__ v,
    const int* __restrict__ src, const int* __restrict__ dst,
    float* __restrict__ wv, float* __restrict__ z, int E)
{
    const int tid = threadIdx.x;      // 0..255
    const int h   = tid >> 5;         // head index
    const int d   = tid & 31;         // dim index within head
    const float inv_scale = 0.17677669529663687f;  // 1/sqrt(32)

    for (int e = blockIdx.x; e < E; e += gridDim.x) {
        const int s = src[e];         // wave-uniform -> scalar load
        const int t = dst[e];

        const float kv = k[(size_t)s * REC + tid];
        const float qv = q[(size_t)t * REC + tid];
        float p = kv * qv;
        // Sum over the 32 lanes of this head (butterfly; all lanes get sum).
        p += __shfl_xor(p, 16, 32);
        p += __shfl_xor(p,  8, 32);
        p += __shfl_xor(p,  4, 32);
        p += __shfl_xor(p,  2, 32);
        p += __shfl_xor(p,  1, 32);

        float sc = p * inv_scale;
        sc = fminf(fmaxf(sc, -5.0f), 5.0f);
        const float score = __expf(sc);

        const float vv = v[(size_t)s * REC + tid];
        atomicAdd(&wv[(size_t)t * REC + tid], vv * score);
        if (d == 0) atomicAdd(&z[(size_t)t * HEADS + h], score);
    }
}

extern "C" void kernel_launch(void* const* d_in, const int* in_sizes, int n_in,
                              void* d_out, int out_size, void* d_ws, size_t ws_size,
                              hipStream_t stream) {
    const float* q  = (const float*)d_in[0];
    const float* k  = (const float*)d_in[1];
    const float* v  = (const float*)d_in[2];
    const int* src  = (const int*)d_in[3];
    const int* dst  = (const int*)d_in[4];
    const int E     = in_sizes[3];
    const int nodes = in_sizes[0] / REC;

    float* wv = (float*)d_out;                       // N*H*DK floats
    float* z  = wv + (size_t)nodes * REC;            // N*H floats

    // d_out is poisoned (0xAA) and never re-poisoned between replays:
    // zero it ourselves every call.
    zero_kernel<<<2048, 256, 0, stream>>>((float*)d_out, out_size);
    edge_kernel<<<2048, 256, 0, stream>>>(q, k, v, src, dst, wv, z, E);
}

// Round 2
// 394.858 us; speedup vs baseline: 2.1654x; 2.1654x over previous
//
#include <hip/hip_runtime.h>
#include <math.h>

// N=50000 nodes, H=8 heads, DK=32. Record = 256 floats = 1KB per node/tensor.
#define HEADS 8
#define DKDIM 32
#define REC   (HEADS * DKDIM)

__global__ void zero_ints(int* __restrict__ p, int n) {
    int i = blockIdx.x * blockDim.x + threadIdx.x;
    int stride = gridDim.x * blockDim.x;
    for (; i < n; i += stride) p[i] = 0;
}

__global__ void hist_kernel(const int* __restrict__ dst, int* __restrict__ hist, int E) {
    int i = blockIdx.x * blockDim.x + threadIdx.x;
    int stride = gridDim.x * blockDim.x;
    for (; i < E; i += stride) atomicAdd(&hist[dst[i]], 1);
}

// Single-block exclusive scan over n (<=~64k) counts -> rowptr.
__global__ __launch_bounds__(1024) void scan_kernel(const int* __restrict__ hist,
                                                    int* __restrict__ rowptr, int n) {
    __shared__ int lds[1024];
    const int t = threadIdx.x;
    const int chunk = (n + 1023) / 1024;
    const int beg = t * chunk;
    const int end = min(beg + chunk, n);
    int s = 0;
    for (int i = beg; i < end; ++i) s += hist[i];
    lds[t] = s;
    __syncthreads();
    // Hillis-Steele inclusive scan over the 1024 partials.
    for (int off = 1; off < 1024; off <<= 1) {
        int val = (t >= off) ? lds[t - off] : 0;
        __syncthreads();
        lds[t] += val;
        __syncthreads();
    }
    int base = (t == 0) ? 0 : lds[t - 1];
    for (int i = beg; i < end; ++i) { rowptr[i] = base; base += hist[i]; }
}

__global__ void scatter_kernel(const int* __restrict__ src, const int* __restrict__ dst,
                               const int* __restrict__ rowptr, int* __restrict__ cnt,
                               int* __restrict__ sorted_src, int E) {
    int i = blockIdx.x * blockDim.x + threadIdx.x;
    int stride = gridDim.x * blockDim.x;
    for (; i < E; i += stride) {
        const int d = dst[i];
        const int pos = rowptr[d] + atomicAdd(&cnt[d], 1);
        sorted_src[pos] = src[i];
    }
}

// One 64-lane wave per destination node. lane -> (head = lane>>3,
// dims [(lane&7)*4 .. +3]) so a wave's float4 load covers one full 1KB record.
__global__ __launch_bounds__(256) void node_kernel(
    const float* __restrict__ q, const float* __restrict__ k,
    const float* __restrict__ v,
    const int* __restrict__ rowptr, const int* __restrict__ hist,
    const int* __restrict__ sorted_src,
    float* __restrict__ wv, float* __restrict__ z, int nodes)
{
    const int lane = threadIdx.x & 63;
    const int node = blockIdx.x * 4 + (threadIdx.x >> 6);
    if (node >= nodes) return;
    const int h = lane >> 3;
    const float inv_scale = 0.17677669529663687f;  // 1/sqrt(32)

    const float4 qf = ((const float4*)(q + (size_t)node * REC))[lane];
    float4 acc = {0.f, 0.f, 0.f, 0.f};
    float zacc = 0.f;

    const int beg = rowptr[node];
    const int end = beg + hist[node];
    for (int i = beg; i < end; ++i) {
        const int s = sorted_src[i];                       // wave-uniform
        const float4 kf = ((const float4*)(k + (size_t)s * REC))[lane];
        float p = kf.x * qf.x + kf.y * qf.y + kf.z * qf.z + kf.w * qf.w;
        p += __shfl_xor(p, 4, 8);
        p += __shfl_xor(p, 2, 8);
        p += __shfl_xor(p, 1, 8);
        float sc = fminf(fmaxf(p * inv_scale, -5.0f), 5.0f);
        const float score = __expf(sc);
        const float4 vf = ((const float4*)(v + (size_t)s * REC))[lane];
        acc.x += vf.x * score;
        acc.y += vf.y * score;
        acc.z += vf.z * score;
        acc.w += vf.w * score;
        zacc += score;
    }
    ((float4*)(wv + (size_t)node * REC))[lane] = acc;
    if ((lane & 7) == 0) z[(size_t)node * HEADS + h] = zacc;
}

extern "C" void kernel_launch(void* const* d_in, const int* in_sizes, int n_in,
                              void* d_out, int out_size, void* d_ws, size_t ws_size,
                              hipStream_t stream) {
    const float* q  = (const float*)d_in[0];
    const float* k  = (const float*)d_in[1];
    const float* v  = (const float*)d_in[2];
    const int* src  = (const int*)d_in[3];
    const int* dst  = (const int*)d_in[4];
    const int E     = in_sizes[3];
    const int nodes = in_sizes[0] / REC;

    float* wv = (float*)d_out;                 // nodes*REC floats
    float* z  = wv + (size_t)nodes * REC;      // nodes*HEADS floats

    // Workspace layout (ints): hist[nodes] | cnt[nodes] | rowptr[nodes] | sorted_src[E]
    int* hist       = (int*)d_ws;
    int* cnt        = hist + nodes;
    int* rowptr     = cnt + nodes;
    int* sorted_src = rowptr + nodes;

    zero_ints<<<256, 256, 0, stream>>>(hist, 2 * nodes);   // hist + cnt
    hist_kernel<<<1024, 256, 0, stream>>>(dst, hist, E);
    scan_kernel<<<1, 1024, 0, stream>>>(hist, rowptr, nodes);
    scatter_kernel<<<1024, 256, 0, stream>>>(src, dst, rowptr, cnt, sorted_src, E);
    node_kernel<<<(nodes + 3) / 4, 256, 0, stream>>>(q, k, v, rowptr, hist, sorted_src,
                                                     wv, z, nodes);
    // Every output element is written unconditionally by node_kernel
    // (degree-0 nodes store zeros), so no output pre-zeroing is needed.
}

// Round 3
// 271.320 us; speedup vs baseline: 3.1513x; 1.4553x over previous
//
#include <hip/hip_runtime.h>
#include <math.h>

// N=50000 nodes, H=8 heads, DK=32. f32 record = 256 floats = 1KB/node/tensor.
#define HEADS 8
#define DKDIM 32
#define REC   (HEADS * DKDIM)

__device__ __forceinline__ unsigned short f2bf_rne(float f) {
    unsigned int u = __float_as_uint(f);
    unsigned int r = u + 0x7fffu + ((u >> 16) & 1u);
    return (unsigned short)(r >> 16);
}
__device__ __forceinline__ float lo16(unsigned int u) { return __uint_as_float(u << 16); }
__device__ __forceinline__ float hi16(unsigned int u) { return __uint_as_float(u & 0xffff0000u); }

__global__ void zero_ints(int* __restrict__ p, int n) {
    int i = blockIdx.x * blockDim.x + threadIdx.x;
    int stride = gridDim.x * blockDim.x;
    for (; i < n; i += stride) p[i] = 0;
}

__global__ void hist_kernel(const int* __restrict__ dst, int* __restrict__ hist, int E) {
    int i = blockIdx.x * blockDim.x + threadIdx.x;
    int stride = gridDim.x * blockDim.x;
    for (; i < E; i += stride) atomicAdd(&hist[dst[i]], 1);
}

// Fused bf16 kv records: per node, 64 chunks of 16B = [k0..k3, v0..v3] bf16.
// Chunk index i = node*64 + p covers k[node*256 + 4p .. +3] / same for v.
__global__ __launch_bounds__(256) void convert_kv(const float* __restrict__ k,
                                                  const float* __restrict__ v,
                                                  uint4* __restrict__ kvb, int total) {
    int i = blockIdx.x * blockDim.x + threadIdx.x;
    int stride = gridDim.x * blockDim.x;
    for (; i < total; i += stride) {
        const float4 kf = ((const float4*)k)[i];
        const float4 vf = ((const float4*)v)[i];
        uint4 o;
        o.x = (unsigned)f2bf_rne(kf.x) | ((unsigned)f2bf_rne(kf.y) << 16);
        o.y = (unsigned)f2bf_rne(kf.z) | ((unsigned)f2bf_rne(kf.w) << 16);
        o.z = (unsigned)f2bf_rne(vf.x) | ((unsigned)f2bf_rne(vf.y) << 16);
        o.w = (unsigned)f2bf_rne(vf.z) | ((unsigned)f2bf_rne(vf.w) << 16);
        kvb[i] = o;
    }
}

// Single-block tiled exclusive scan, wave-shuffle based (3 syncs/tile).
__global__ __launch_bounds__(1024) void scan_kernel(const int* __restrict__ hist,
                                                    int* __restrict__ rowptr, int n) {
    __shared__ int wsum[16];
    __shared__ int wbase[16];
    __shared__ int s_total;
    const int t = threadIdx.x;
    const int lane = t & 63;
    const int wid = t >> 6;
    int base = 0;
    for (int tile0 = 0; tile0 < n; tile0 += 1024) {
        const int i = tile0 + t;
        int x = (i < n) ? hist[i] : 0;
        int inc = x;
        #pragma unroll
        for (int off = 1; off < 64; off <<= 1) {
            int y = __shfl_up(inc, off, 64);
            if (lane >= off) inc += y;
        }
        if (lane == 63) wsum[wid] = inc;
        __syncthreads();
        if (t < 16) {
            int w = wsum[t];
            int winc = w;
            #pragma unroll
            for (int off = 1; off < 16; off <<= 1) {
                int y = __shfl_up(winc, off, 16);
                if (t >= off) winc += y;
            }
            wbase[t] = winc - w;
            if (t == 15) s_total = winc;
        }
        __syncthreads();
        if (i < n) rowptr[i] = base + wbase[wid] + inc - x;
        int tt = s_total;
        __syncthreads();
        base += tt;
    }
}

__global__ void scatter_kernel(const int* __restrict__ src, const int* __restrict__ dst,
                               const int* __restrict__ rowptr, int* __restrict__ cnt,
                               int* __restrict__ sorted_src, int E) {
    int i = blockIdx.x * blockDim.x + threadIdx.x;
    int stride = gridDim.x * blockDim.x;
    for (; i < E; i += stride) {
        const int d = dst[i];
        const int pos = rowptr[d] + atomicAdd(&cnt[d], 1);
        sorted_src[pos] = src[i];
    }
}

// One 64-lane wave per destination node; lane -> (head = lane>>3, 4 dims).
// Per edge: one uint4 (16B) load/lane from the fused kv record (1KB/wave).
__global__ __launch_bounds__(256) void node_kernel_bf16(
    const float* __restrict__ q, const uint4* __restrict__ kvb,
    const int* __restrict__ rowptr, const int* __restrict__ hist,
    const int* __restrict__ sorted_src,
    float* __restrict__ wv, float* __restrict__ z, int nodes)
{
    const int lane = threadIdx.x & 63;
    const int node = blockIdx.x * 4 + (threadIdx.x >> 6);
    if (node >= nodes) return;
    const int h = lane >> 3;
    const float inv_scale = 0.17677669529663687f;  // 1/sqrt(32)

    const float4 qf = ((const float4*)(q + (size_t)node * REC))[lane];
    float4 acc = {0.f, 0.f, 0.f, 0.f};
    float zacc = 0.f;

    const int beg = rowptr[node];
    const int end = beg + hist[node];
    int i = beg;
    for (; i + 1 < end; i += 2) {
        const int s0 = sorted_src[i];
        const int s1 = sorted_src[i + 1];
        const uint4 c0 = kvb[(size_t)s0 * 64 + lane];
        const uint4 c1 = kvb[(size_t)s1 * 64 + lane];

        float p0 = lo16(c0.x) * qf.x + hi16(c0.x) * qf.y
                 + lo16(c0.y) * qf.z + hi16(c0.y) * qf.w;
        float p1 = lo16(c1.x) * qf.x + hi16(c1.x) * qf.y
                 + lo16(c1.y) * qf.z + hi16(c1.y) * qf.w;
        p0 += __shfl_xor(p0, 4, 8); p1 += __shfl_xor(p1, 4, 8);
        p0 += __shfl_xor(p0, 2, 8); p1 += __shfl_xor(p1, 2, 8);
        p0 += __shfl_xor(p0, 1, 8); p1 += __shfl_xor(p1, 1, 8);
        const float sc0 = __expf(fminf(fmaxf(p0 * inv_scale, -5.0f), 5.0f));
        const float sc1 = __expf(fminf(fmaxf(p1 * inv_scale, -5.0f), 5.0f));

        acc.x += lo16(c0.z) * sc0 + lo16(c1.z) * sc1;
        acc.y += hi16(c0.z) * sc0 + hi16(c1.z) * sc1;
        acc.z += lo16(c0.w) * sc0 + lo16(c1.w) * sc1;
        acc.w += hi16(c0.w) * sc0 + hi16(c1.w) * sc1;
        zacc += sc0 + sc1;
    }
    if (i < end) {
        const int s0 = sorted_src[i];
        const uint4 c0 = kvb[(size_t)s0 * 64 + lane];
        float p0 = lo16(c0.x) * qf.x + hi16(c0.x) * qf.y
                 + lo16(c0.y) * qf.z + hi16(c0.y) * qf.w;
        p0 += __shfl_xor(p0, 4, 8);
        p0 += __shfl_xor(p0, 2, 8);
        p0 += __shfl_xor(p0, 1, 8);
        const float sc0 = __expf(fminf(fmaxf(p0 * inv_scale, -5.0f), 5.0f));
        acc.x += lo16(c0.z) * sc0;
        acc.y += hi16(c0.z) * sc0;
        acc.z += lo16(c0.w) * sc0;
        acc.w += hi16(c0.w) * sc0;
        zacc += sc0;
    }
    ((float4*)(wv + (size_t)node * REC))[lane] = acc;
    if ((lane & 7) == 0) z[(size_t)node * HEADS + h] = zacc;
}

// f32 fallback (round-2 kernel) if ws_size can't hold the bf16 kv copy.
__global__ __launch_bounds__(256) void node_kernel_f32(
    const float* __restrict__ q, const float* __restrict__ k,
    const float* __restrict__ v,
    const int* __restrict__ rowptr, const int* __restrict__ hist,
    const int* __restrict__ sorted_src,
    float* __restrict__ wv, float* __restrict__ z, int nodes)
{
    const int lane = threadIdx.x & 63;
    const int node = blockIdx.x * 4 + (threadIdx.x >> 6);
    if (node >= nodes) return;
    const int h = lane >> 3;
    const float inv_scale = 0.17677669529663687f;

    const float4 qf = ((const float4*)(q + (size_t)node * REC))[lane];
    float4 acc = {0.f, 0.f, 0.f, 0.f};
    float zacc = 0.f;

    const int beg = rowptr[node];
    const int end = beg + hist[node];
    for (int i = beg; i < end; ++i) {
        const int s = sorted_src[i];
        const float4 kf = ((const float4*)(k + (size_t)s * REC))[lane];
        float p = kf.x * qf.x + kf.y * qf.y + kf.z * qf.z + kf.w * qf.w;
        p += __shfl_xor(p, 4, 8);
        p += __shfl_xor(p, 2, 8);
        p += __shfl_xor(p, 1, 8);
        const float score = __expf(fminf(fmaxf(p * inv_scale, -5.0f), 5.0f));
        const float4 vf = ((const float4*)(v + (size_t)s * REC))[lane];
        acc.x += vf.x * score;
        acc.y += vf.y * score;
        acc.z += vf.z * score;
        acc.w += vf.w * score;
        zacc += score;
    }
    ((float4*)(wv + (size_t)node * REC))[lane] = acc;
    if ((lane & 7) == 0) z[(size_t)node * HEADS + h] = zacc;
}

extern "C" void kernel_launch(void* const* d_in, const int* in_sizes, int n_in,
                              void* d_out, int out_size, void* d_ws, size_t ws_size,
                              hipStream_t stream) {
    const float* q  = (const float*)d_in[0];
    const float* k  = (const float*)d_in[1];
    const float* v  = (const float*)d_in[2];
    const int* src  = (const int*)d_in[3];
    const int* dst  = (const int*)d_in[4];
    const int E     = in_sizes[3];
    const int nodes = in_sizes[0] / REC;

    float* wv = (float*)d_out;                 // nodes*REC floats
    float* z  = wv + (size_t)nodes * REC;      // nodes*HEADS floats

    const size_t kv_bytes  = (size_t)nodes * 64 * sizeof(uint4);   // 1KB/node
    const size_t int_count = (size_t)3 * nodes + (size_t)E;
    const bool use_bf16 = ws_size >= kv_bytes + int_count * sizeof(int);

    char* wsb = (char*)d_ws;
    uint4* kvb = (uint4*)wsb;
    int* ints  = use_bf16 ? (int*)(wsb + kv_bytes) : (int*)wsb;
    int* hist       = ints;
    int* cnt        = hist + nodes;
    int* rowptr     = cnt + nodes;
    int* sorted_src = rowptr + nodes;

    zero_ints<<<256, 256, 0, stream>>>(hist, 2 * nodes);   // hist + cnt
    hist_kernel<<<1024, 256, 0, stream>>>(dst, hist, E);
    if (use_bf16)
        convert_kv<<<2048, 256, 0, stream>>>(k, v, kvb, nodes * 64);
    scan_kernel<<<1, 1024, 0, stream>>>(hist, rowptr, nodes);
    scatter_kernel<<<1024, 256, 0, stream>>>(src, dst, rowptr, cnt, sorted_src, E);
    if (use_bf16)
        node_kernel_bf16<<<(nodes + 3) / 4, 256, 0, stream>>>(q, kvb, rowptr, hist,
                                                              sorted_src, wv, z, nodes);
    else
        node_kernel_f32<<<(nodes + 3) / 4, 256, 0, stream>>>(q, k, v, rowptr, hist,
                                                             sorted_src, wv, z, nodes);
}

// Round 4
// 240.031 us; speedup vs baseline: 3.5621x; 1.1304x over previous
//
#include <hip/hip_runtime.h>
#include <math.h>

// N=50000 nodes, H=8 heads, DK=32. f32 record = 256 floats = 1KB/node/tensor.
#define HEADS 8
#define DKDIM 32
#define REC   (HEADS * DKDIM)

__device__ __forceinline__ unsigned short f2bf_rne(float f) {
    unsigned int u = __float_as_uint(f);
    unsigned int r = u + 0x7fffu + ((u >> 16) & 1u);
    return (unsigned short)(r >> 16);
}
__device__ __forceinline__ float lo16(unsigned int u) { return __uint_as_float(u << 16); }
__device__ __forceinline__ float hi16(unsigned int u) { return __uint_as_float(u & 0xffff0000u); }

// Fused: (a) bf16 kv records -- per node 64 chunks of 16B = [k0..k3,v0..v3] bf16;
// (b) histogram of dst. Independent grid-stride loops, one dispatch.
__global__ __launch_bounds__(256) void prep_kernel(
    const float* __restrict__ k, const float* __restrict__ v,
    uint4* __restrict__ kvb, int total_chunks,
    const int* __restrict__ dst, int* __restrict__ hist, int E)
{
    const int stride = gridDim.x * blockDim.x;
    for (int i = blockIdx.x * blockDim.x + threadIdx.x; i < total_chunks; i += stride) {
        const float4 kf = ((const float4*)k)[i];
        const float4 vf = ((const float4*)v)[i];
        uint4 o;
        o.x = (unsigned)f2bf_rne(kf.x) | ((unsigned)f2bf_rne(kf.y) << 16);
        o.y = (unsigned)f2bf_rne(kf.z) | ((unsigned)f2bf_rne(kf.w) << 16);
        o.z = (unsigned)f2bf_rne(vf.x) | ((unsigned)f2bf_rne(vf.y) << 16);
        o.w = (unsigned)f2bf_rne(vf.z) | ((unsigned)f2bf_rne(vf.w) << 16);
        kvb[i] = o;
    }
    for (int i = blockIdx.x * blockDim.x + threadIdx.x; i < E; i += stride) {
        atomicAdd(&hist[dst[i]], 1);
    }
}

// Two-level parallel scan over hist[n] -> exclusive rowptr[n].
__global__ __launch_bounds__(256) void scan_part_kernel(const int* __restrict__ hist,
                                                        int* __restrict__ bsum, int n) {
    const int t = threadIdx.x, lane = t & 63, wid = t >> 6;
    const int i = blockIdx.x * 256 + t;
    int x = (i < n) ? hist[i] : 0;
    #pragma unroll
    for (int off = 1; off < 64; off <<= 1) x += __shfl_xor(x, off, 64);
    __shared__ int ws[4];
    if (lane == 0) ws[wid] = x;
    __syncthreads();
    if (t == 0) bsum[blockIdx.x] = ws[0] + ws[1] + ws[2] + ws[3];
}

__global__ __launch_bounds__(256) void scan_block_kernel(int* __restrict__ bsum, int nb) {
    const int t = threadIdx.x, lane = t & 63, wid = t >> 6;
    int x = (t < nb) ? bsum[t] : 0;
    int inc = x;
    #pragma unroll
    for (int off = 1; off < 64; off <<= 1) {
        int y = __shfl_up(inc, off, 64);
        if (lane >= off) inc += y;
    }
    __shared__ int ws[4];
    if (lane == 63) ws[wid] = inc;
    __syncthreads();
    int base = 0;
    for (int w = 0; w < wid; ++w) base += ws[w];
    if (t < nb) bsum[t] = base + inc - x;   // exclusive base per block
}

__global__ __launch_bounds__(256) void scan_fix_kernel(const int* __restrict__ hist,
                                                       const int* __restrict__ bsum,
                                                       int* __restrict__ rowptr, int n) {
    const int t = threadIdx.x, lane = t & 63, wid = t >> 6;
    const int i = blockIdx.x * 256 + t;
    int x = (i < n) ? hist[i] : 0;
    int inc = x;
    #pragma unroll
    for (int off = 1; off < 64; off <<= 1) {
        int y = __shfl_up(inc, off, 64);
        if (lane >= off) inc += y;
    }
    __shared__ int ws[4];
    if (lane == 63) ws[wid] = inc;
    __syncthreads();
    int base = bsum[blockIdx.x];
    for (int w = 0; w < wid; ++w) base += ws[w];
    if (i < n) rowptr[i] = base + inc - x;
}

// Scatter using rowptr itself as the cursor: afterwards rowptr[d] == end(d).
__global__ void scatter_kernel(const int* __restrict__ src, const int* __restrict__ dst,
                               int* __restrict__ rowptr,
                               int* __restrict__ sorted_src, int E) {
    int i = blockIdx.x * blockDim.x + threadIdx.x;
    const int stride = gridDim.x * blockDim.x;
    for (; i < E; i += stride) {
        const int pos = atomicAdd(&rowptr[dst[i]], 1);
        sorted_src[pos] = src[i];
    }
}

// One 64-lane wave per destination node; lane -> (head = lane>>3, 4 dims).
// Per edge: one uint4 (16B) load/lane from the fused kv record (1KB/wave).
// rowptr[node] is END after scatter; beg = end - hist[node]. 4-wide unroll.
__global__ __launch_bounds__(256) void node_kernel_bf16(
    const float* __restrict__ q, const uint4* __restrict__ kvb,
    const int* __restrict__ rowptr, const int* __restrict__ hist,
    const int* __restrict__ sorted_src,
    float* __restrict__ wv, float* __restrict__ z, int nodes)
{
    const int lane = threadIdx.x & 63;
    const int node = blockIdx.x * 4 + (threadIdx.x >> 6);
    if (node >= nodes) return;
    const int h = lane >> 3;
    const float inv_scale = 0.17677669529663687f;  // 1/sqrt(32)

    const float4 qf = ((const float4*)(q + (size_t)node * REC))[lane];
    float4 acc = {0.f, 0.f, 0.f, 0.f};
    float zacc = 0.f;

    const int end = rowptr[node];
    const int beg = end - hist[node];
    int i = beg;
    for (; i + 3 < end; i += 4) {
        const int s0 = sorted_src[i];
        const int s1 = sorted_src[i + 1];
        const int s2 = sorted_src[i + 2];
        const int s3 = sorted_src[i + 3];
        const uint4 c0 = kvb[(size_t)s0 * 64 + lane];
        const uint4 c1 = kvb[(size_t)s1 * 64 + lane];
        const uint4 c2 = kvb[(size_t)s2 * 64 + lane];
        const uint4 c3 = kvb[(size_t)s3 * 64 + lane];

        float p0 = lo16(c0.x) * qf.x + hi16(c0.x) * qf.y + lo16(c0.y) * qf.z + hi16(c0.y) * qf.w;
        float p1 = lo16(c1.x) * qf.x + hi16(c1.x) * qf.y + lo16(c1.y) * qf.z + hi16(c1.y) * qf.w;
        float p2 = lo16(c2.x) * qf.x + hi16(c2.x) * qf.y + lo16(c2.y) * qf.z + hi16(c2.y) * qf.w;
        float p3 = lo16(c3.x) * qf.x + hi16(c3.x) * qf.y + lo16(c3.y) * qf.z + hi16(c3.y) * qf.w;
        p0 += __shfl_xor(p0, 4, 8); p1 += __shfl_xor(p1, 4, 8);
        p2 += __shfl_xor(p2, 4, 8); p3 += __shfl_xor(p3, 4, 8);
        p0 += __shfl_xor(p0, 2, 8); p1 += __shfl_xor(p1, 2, 8);
        p2 += __shfl_xor(p2, 2, 8); p3 += __shfl_xor(p3, 2, 8);
        p0 += __shfl_xor(p0, 1, 8); p1 += __shfl_xor(p1, 1, 8);
        p2 += __shfl_xor(p2, 1, 8); p3 += __shfl_xor(p3, 1, 8);
        const float sc0 = __expf(fminf(fmaxf(p0 * inv_scale, -5.0f), 5.0f));
        const float sc1 = __expf(fminf(fmaxf(p1 * inv_scale, -5.0f), 5.0f));
        const float sc2 = __expf(fminf(fmaxf(p2 * inv_scale, -5.0f), 5.0f));
        const float sc3 = __expf(fminf(fmaxf(p3 * inv_scale, -5.0f), 5.0f));

        acc.x += lo16(c0.z) * sc0 + lo16(c1.z) * sc1 + lo16(c2.z) * sc2 + lo16(c3.z) * sc3;
        acc.y += hi16(c0.z) * sc0 + hi16(c1.z) * sc1 + hi16(c2.z) * sc2 + hi16(c3.z) * sc3;
        acc.z += lo16(c0.w) * sc0 + lo16(c1.w) * sc1 + lo16(c2.w) * sc2 + lo16(c3.w) * sc3;
        acc.w += hi16(c0.w) * sc0 + hi16(c1.w) * sc1 + hi16(c2.w) * sc2 + hi16(c3.w) * sc3;
        zacc += (sc0 + sc1) + (sc2 + sc3);
    }
    for (; i < end; ++i) {
        const int s0 = sorted_src[i];
        const uint4 c0 = kvb[(size_t)s0 * 64 + lane];
        float p0 = lo16(c0.x) * qf.x + hi16(c0.x) * qf.y + lo16(c0.y) * qf.z + hi16(c0.y) * qf.w;
        p0 += __shfl_xor(p0, 4, 8);
        p0 += __shfl_xor(p0, 2, 8);
        p0 += __shfl_xor(p0, 1, 8);
        const float sc0 = __expf(fminf(fmaxf(p0 * inv_scale, -5.0f), 5.0f));
        acc.x += lo16(c0.z) * sc0;
        acc.y += hi16(c0.z) * sc0;
        acc.z += lo16(c0.w) * sc0;
        acc.w += hi16(c0.w) * sc0;
        zacc += sc0;
    }
    ((float4*)(wv + (size_t)node * REC))[lane] = acc;
    if ((lane & 7) == 0) z[(size_t)node * HEADS + h] = zacc;
}

// f32 fallback if ws can't hold the bf16 kv copy (same CSR pipeline).
__global__ __launch_bounds__(256) void node_kernel_f32(
    const float* __restrict__ q, const float* __restrict__ k,
    const float* __restrict__ v,
    const int* __restrict__ rowptr, const int* __restrict__ hist,
    const int* __restrict__ sorted_src,
    float* __restrict__ wv, float* __restrict__ z, int nodes)
{
    const int lane = threadIdx.x & 63;
    const int node = blockIdx.x * 4 + (threadIdx.x >> 6);
    if (node >= nodes) return;
    const int h = lane >> 3;
    const float inv_scale = 0.17677669529663687f;

    const float4 qf = ((const float4*)(q + (size_t)node * REC))[lane];
    float4 acc = {0.f, 0.f, 0.f, 0.f};
    float zacc = 0.f;

    const int end = rowptr[node];
    const int beg = end - hist[node];
    for (int i = beg; i < end; ++i) {
        const int s = sorted_src[i];
        const float4 kf = ((const float4*)(k + (size_t)s * REC))[lane];
        float p = kf.x * qf.x + kf.y * qf.y + kf.z * qf.z + kf.w * qf.w;
        p += __shfl_xor(p, 4, 8);
        p += __shfl_xor(p, 2, 8);
        p += __shfl_xor(p, 1, 8);
        const float score = __expf(fminf(fmaxf(p * inv_scale, -5.0f), 5.0f));
        const float4 vf = ((const float4*)(v + (size_t)s * REC))[lane];
        acc.x += vf.x * score;
        acc.y += vf.y * score;
        acc.z += vf.z * score;
        acc.w += vf.w * score;
        zacc += score;
    }
    ((float4*)(wv + (size_t)node * REC))[lane] = acc;
    if ((lane & 7) == 0) z[(size_t)node * HEADS + h] = zacc;
}

extern "C" void kernel_launch(void* const* d_in, const int* in_sizes, int n_in,
                              void* d_out, int out_size, void* d_ws, size_t ws_size,
                              hipStream_t stream) {
    const float* q  = (const float*)d_in[0];
    const float* k  = (const float*)d_in[1];
    const float* v  = (const float*)d_in[2];
    const int* src  = (const int*)d_in[3];
    const int* dst  = (const int*)d_in[4];
    const int E     = in_sizes[3];
    const int nodes = in_sizes[0] / REC;

    float* wv = (float*)d_out;                 // nodes*REC floats
    float* z  = wv + (size_t)nodes * REC;      // nodes*HEADS floats

    const int nb = (nodes + 255) / 256;        // scan blocks
    const size_t kv_bytes  = (size_t)nodes * 64 * sizeof(uint4);   // 1KB/node
    const size_t int_count = (size_t)2 * nodes + nb + (size_t)E;
    const bool use_bf16 = ws_size >= kv_bytes + int_count * sizeof(int);

    char* wsb = (char*)d_ws;
    uint4* kvb = (uint4*)wsb;
    int* ints  = use_bf16 ? (int*)(wsb + kv_bytes) : (int*)wsb;
    int* hist       = ints;
    int* rowptr     = hist + nodes;
    int* bsum       = rowptr + nodes;
    int* sorted_src = bsum + nb;

    hipMemsetAsync(hist, 0, (size_t)nodes * sizeof(int), stream);
    if (use_bf16) {
        prep_kernel<<<2048, 256, 0, stream>>>(k, v, kvb, nodes * 64, dst, hist, E);
    } else {
        prep_kernel<<<2048, 256, 0, stream>>>(k, v, kvb, 0, dst, hist, E);
    }
    scan_part_kernel<<<nb, 256, 0, stream>>>(hist, bsum, nodes);
    scan_block_kernel<<<1, 256, 0, stream>>>(bsum, nb);
    scan_fix_kernel<<<nb, 256, 0, stream>>>(hist, bsum, rowptr, nodes);
    scatter_kernel<<<1024, 256, 0, stream>>>(src, dst, rowptr, sorted_src, E);
    if (use_bf16)
        node_kernel_bf16<<<(nodes + 3) / 4, 256, 0, stream>>>(q, kvb, rowptr, hist,
                                                              sorted_src, wv, z, nodes);
    else
        node_kernel_f32<<<(nodes + 3) / 4, 256, 0, stream>>>(q, k, v, rowptr, hist,
                                                             sorted_src, wv, z, nodes);
}

// Round 5
// 235.105 us; speedup vs baseline: 3.6367x; 1.0210x over previous
//
#include <hip/hip_runtime.h>
#include <math.h>

// N=50000 nodes, H=8 heads, DK=32. f32 record = 256 floats = 1KB/node/tensor.
#define HEADS 8
#define DKDIM 32
#define REC   (HEADS * DKDIM)

__device__ __forceinline__ unsigned short f2bf_rne(float f) {
    unsigned int u = __float_as_uint(f);
    unsigned int r = u + 0x7fffu + ((u >> 16) & 1u);
    return (unsigned short)(r >> 16);
}
__device__ __forceinline__ float lo16(unsigned int u) { return __uint_as_float(u << 16); }
__device__ __forceinline__ float hi16(unsigned int u) { return __uint_as_float(u & 0xffff0000u); }

// Histogram of composite key (dst<<bandsL) | (src>>shift).
__global__ __launch_bounds__(256) void hist_kernel(
    const int* __restrict__ src, const int* __restrict__ dst,
    int* __restrict__ hist, int E, int bandsL, int shift)
{
    int i = blockIdx.x * blockDim.x + threadIdx.x;
    const int stride = gridDim.x * blockDim.x;
    for (; i < E; i += stride) {
        const int key = (dst[i] << bandsL) | (src[i] >> shift);
        atomicAdd(&hist[key], 1);
    }
}

// Two-level scan stage 1: per-256-block sums of hist.
__global__ __launch_bounds__(256) void scan_part_kernel(const int* __restrict__ hist,
                                                        int* __restrict__ bsum, int n) {
    const int t = threadIdx.x, lane = t & 63, wid = t >> 6;
    const int i = blockIdx.x * 256 + t;
    int x = (i < n) ? hist[i] : 0;
    #pragma unroll
    for (int off = 1; off < 64; off <<= 1) x += __shfl_xor(x, off, 64);
    __shared__ int ws[4];
    if (lane == 0) ws[wid] = x;
    __syncthreads();
    if (t == 0) bsum[blockIdx.x] = ws[0] + ws[1] + ws[2] + ws[3];
}

// Stage 2: single-block tiled in-place EXCLUSIVE scan of bsum[nb] (nb up to ~8k).
__global__ __launch_bounds__(1024) void scan_mid_kernel(int* __restrict__ bsum, int n) {
    __shared__ int wsum[16];
    __shared__ int wbase[16];
    __shared__ int s_total;
    const int t = threadIdx.x;
    const int lane = t & 63;
    const int wid = t >> 6;
    int base = 0;
    for (int tile0 = 0; tile0 < n; tile0 += 1024) {
        const int i = tile0 + t;
        int x = (i < n) ? bsum[i] : 0;
        int inc = x;
        #pragma unroll
        for (int off = 1; off < 64; off <<= 1) {
            int y = __shfl_up(inc, off, 64);
            if (lane >= off) inc += y;
        }
        if (lane == 63) wsum[wid] = inc;
        __syncthreads();
        if (t < 16) {
            int w = wsum[t];
            int winc = w;
            #pragma unroll
            for (int off = 1; off < 16; off <<= 1) {
                int y = __shfl_up(winc, off, 16);
                if (t >= off) winc += y;
            }
            wbase[t] = winc - w;
            if (t == 15) s_total = winc;
        }
        __syncthreads();
        if (i < n) bsum[i] = base + wbase[wid] + inc - x;
        int tt = s_total;
        __syncthreads();
        base += tt;
    }
}

// Stage 3: rowptr[i] = bsum[block] + intra-block exclusive prefix.
__global__ __launch_bounds__(256) void scan_fix_kernel(const int* __restrict__ hist,
                                                       const int* __restrict__ bsum,
                                                       int* __restrict__ rowptr, int n) {
    const int t = threadIdx.x, lane = t & 63, wid = t >> 6;
    const int i = blockIdx.x * 256 + t;
    int x = (i < n) ? hist[i] : 0;
    int inc = x;
    #pragma unroll
    for (int off = 1; off < 64; off <<= 1) {
        int y = __shfl_up(inc, off, 64);
        if (lane >= off) inc += y;
    }
    __shared__ int ws[4];
    if (lane == 63) ws[wid] = inc;
    __syncthreads();
    int base = bsum[blockIdx.x];
    for (int w = 0; w < wid; ++w) base += ws[w];
    if (i < n) rowptr[i] = base + inc - x;
}

// Fused: (a) scatter edges into banded-CSR order (rowptr preserved; cnt is the
// cursor); (b) f32->bf16 kv conversion (independent grid-stride loop).
// kv record: per node 64 chunks of 16B = [k0..k3, v0..v3] bf16.
__global__ __launch_bounds__(256) void scatter_convert_kernel(
    const int* __restrict__ src, const int* __restrict__ dst,
    const int* __restrict__ rowptr, int* __restrict__ cnt,
    int* __restrict__ sorted_src, int E, int bandsL, int shift,
    const float* __restrict__ k, const float* __restrict__ v,
    uint4* __restrict__ kvb, int total_chunks)
{
    const int stride = gridDim.x * blockDim.x;
    for (int i = blockIdx.x * blockDim.x + threadIdx.x; i < E; i += stride) {
        const int s = src[i];
        const int key = (dst[i] << bandsL) | (s >> shift);
        const int pos = rowptr[key] + atomicAdd(&cnt[key], 1);
        sorted_src[pos] = s;
    }
    for (int i = blockIdx.x * blockDim.x + threadIdx.x; i < total_chunks; i += stride) {
        const float4 kf = ((const float4*)k)[i];
        const float4 vf = ((const float4*)v)[i];
        uint4 o;
        o.x = (unsigned)f2bf_rne(kf.x) | ((unsigned)f2bf_rne(kf.y) << 16);
        o.y = (unsigned)f2bf_rne(kf.z) | ((unsigned)f2bf_rne(kf.w) << 16);
        o.z = (unsigned)f2bf_rne(vf.x) | ((unsigned)f2bf_rne(vf.y) << 16);
        o.w = (unsigned)f2bf_rne(vf.z) | ((unsigned)f2bf_rne(vf.w) << 16);
        kvb[i] = o;
    }
}

// One 64-lane wave per destination node; lane -> (head = lane>>3, 4 dims).
// Per edge: one uint4 (16B) load/lane from the fused kv record (1KB/wave).
// Edge range: [rowptr[node<<bandsL], rowptr[(node+1)<<bandsL]) (E sentinel).
__global__ __launch_bounds__(256) void node_kernel_bf16(
    const float* __restrict__ q, const uint4* __restrict__ kvb,
    const int* __restrict__ rowptr, const int* __restrict__ sorted_src,
    float* __restrict__ wv, float* __restrict__ z, int nodes, int bandsL, int E)
{
    const int lane = threadIdx.x & 63;
    const int node = blockIdx.x * 4 + (threadIdx.x >> 6);
    if (node >= nodes) return;
    const int h = lane >> 3;
    const float inv_scale = 0.17677669529663687f;  // 1/sqrt(32)

    const float4 qf = ((const float4*)(q + (size_t)node * REC))[lane];
    float4 acc = {0.f, 0.f, 0.f, 0.f};
    float zacc = 0.f;

    const int beg = rowptr[node << bandsL];
    const int end = (node + 1 < nodes) ? rowptr[(node + 1) << bandsL] : E;
    int i = beg;
    for (; i + 1 < end; i += 2) {
        const int s0 = sorted_src[i];
        const int s1 = sorted_src[i + 1];
        const uint4 c0 = kvb[(size_t)s0 * 64 + lane];
        const uint4 c1 = kvb[(size_t)s1 * 64 + lane];

        float p0 = lo16(c0.x) * qf.x + hi16(c0.x) * qf.y
                 + lo16(c0.y) * qf.z + hi16(c0.y) * qf.w;
        float p1 = lo16(c1.x) * qf.x + hi16(c1.x) * qf.y
                 + lo16(c1.y) * qf.z + hi16(c1.y) * qf.w;
        p0 += __shfl_xor(p0, 4, 8); p1 += __shfl_xor(p1, 4, 8);
        p0 += __shfl_xor(p0, 2, 8); p1 += __shfl_xor(p1, 2, 8);
        p0 += __shfl_xor(p0, 1, 8); p1 += __shfl_xor(p1, 1, 8);
        const float sc0 = __expf(fminf(fmaxf(p0 * inv_scale, -5.0f), 5.0f));
        const float sc1 = __expf(fminf(fmaxf(p1 * inv_scale, -5.0f), 5.0f));

        acc.x += lo16(c0.z) * sc0 + lo16(c1.z) * sc1;
        acc.y += hi16(c0.z) * sc0 + hi16(c1.z) * sc1;
        acc.z += lo16(c0.w) * sc0 + lo16(c1.w) * sc1;
        acc.w += hi16(c0.w) * sc0 + hi16(c1.w) * sc1;
        zacc += sc0 + sc1;
    }
    if (i < end) {
        const int s0 = sorted_src[i];
        const uint4 c0 = kvb[(size_t)s0 * 64 + lane];
        float p0 = lo16(c0.x) * qf.x + hi16(c0.x) * qf.y
                 + lo16(c0.y) * qf.z + hi16(c0.y) * qf.w;
        p0 += __shfl_xor(p0, 4, 8);
        p0 += __shfl_xor(p0, 2, 8);
        p0 += __shfl_xor(p0, 1, 8);
        const float sc0 = __expf(fminf(fmaxf(p0 * inv_scale, -5.0f), 5.0f));
        acc.x += lo16(c0.z) * sc0;
        acc.y += hi16(c0.z) * sc0;
        acc.z += lo16(c0.w) * sc0;
        acc.w += hi16(c0.w) * sc0;
        zacc += sc0;
    }
    ((float4*)(wv + (size_t)node * REC))[lane] = acc;
    if ((lane & 7) == 0) z[(size_t)node * HEADS + h] = zacc;
}

// f32 fallback if ws can't hold the bf16 kv copy (same CSR pipeline, bands=1).
__global__ __launch_bounds__(256) void node_kernel_f32(
    const float* __restrict__ q, const float* __restrict__ k,
    const float* __restrict__ v,
    const int* __restrict__ rowptr, const int* __restrict__ sorted_src,
    float* __restrict__ wv, float* __restrict__ z, int nodes, int bandsL, int E)
{
    const int lane = threadIdx.x & 63;
    const int node = blockIdx.x * 4 + (threadIdx.x >> 6);
    if (node >= nodes) return;
    const int h = lane >> 3;
    const float inv_scale = 0.17677669529663687f;

    const float4 qf = ((const float4*)(q + (size_t)node * REC))[lane];
    float4 acc = {0.f, 0.f, 0.f, 0.f};
    float zacc = 0.f;

    const int beg = rowptr[node << bandsL];
    const int end = (node + 1 < nodes) ? rowptr[(node + 1) << bandsL] : E;
    for (int i = beg; i < end; ++i) {
        const int s = sorted_src[i];
        const float4 kf = ((const float4*)(k + (size_t)s * REC))[lane];
        float p = kf.x * qf.x + kf.y * qf.y + kf.z * qf.z + kf.w * qf.w;
        p += __shfl_xor(p, 4, 8);
        p += __shfl_xor(p, 2, 8);
        p += __shfl_xor(p, 1, 8);
        const float score = __expf(fminf(fmaxf(p * inv_scale, -5.0f), 5.0f));
        const float4 vf = ((const float4*)(v + (size_t)s * REC))[lane];
        acc.x += vf.x * score;
        acc.y += vf.y * score;
        acc.z += vf.z * score;
        acc.w += vf.w * score;
        zacc += score;
    }
    ((float4*)(wv + (size_t)node * REC))[lane] = acc;
    if ((lane & 7) == 0) z[(size_t)node * HEADS + h] = zacc;
}

extern "C" void kernel_launch(void* const* d_in, const int* in_sizes, int n_in,
                              void* d_out, int out_size, void* d_ws, size_t ws_size,
                              hipStream_t stream) {
    const float* q  = (const float*)d_in[0];
    const float* k  = (const float*)d_in[1];
    const float* v  = (const float*)d_in[2];
    const int* src  = (const int*)d_in[3];
    const int* dst  = (const int*)d_in[4];
    const int E     = in_sizes[3];
    const int nodes = in_sizes[0] / REC;

    float* wv = (float*)d_out;                 // nodes*REC floats
    float* z  = wv + (size_t)nodes * REC;      // nodes*HEADS floats

    const size_t kv_bytes = (size_t)nodes * 64 * sizeof(uint4);   // 1KB/node

    // Pick bands: 16 (src>>12) if workspace fits, else 1 (plain dst sort).
    // ws ints needed: 3*NB (hist,cnt,rowptr) + nbp (bsum) + E (sorted_src).
    auto ints_needed = [&](int bandsL) -> size_t {
        const size_t NB = (size_t)nodes << bandsL;
        const size_t nbp = (NB + 255) / 256;
        return 3 * NB + nbp + (size_t)E;
    };
    int bandsL;
    bool use_bf16;
    if (ws_size >= kv_bytes + ints_needed(4) * sizeof(int)) {
        bandsL = 4; use_bf16 = true;
    } else if (ws_size >= kv_bytes + ints_needed(0) * sizeof(int)) {
        bandsL = 0; use_bf16 = true;
    } else {
        bandsL = 0; use_bf16 = false;
    }
    const int shift = 16 - bandsL;             // src < 65536 -> band < 2^bandsL
    const int NB  = nodes << bandsL;
    const int nbp = (NB + 255) / 256;

    char* wsb = (char*)d_ws;
    uint4* kvb = (uint4*)wsb;
    int* ints  = use_bf16 ? (int*)(wsb + kv_bytes) : (int*)wsb;
    int* hist       = ints;                    // NB
    int* cnt        = hist + NB;               // NB (contiguous with hist for memset)
    int* rowptr     = cnt + NB;                // NB
    int* bsum       = rowptr + NB;             // nbp
    int* sorted_src = bsum + nbp;              // E

    hipMemsetAsync(hist, 0, (size_t)2 * NB * sizeof(int), stream);  // hist + cnt
    hist_kernel<<<1024, 256, 0, stream>>>(src, dst, hist, E, bandsL, shift);
    scan_part_kernel<<<nbp, 256, 0, stream>>>(hist, bsum, NB);
    scan_mid_kernel<<<1, 1024, 0, stream>>>(bsum, nbp);
    scan_fix_kernel<<<nbp, 256, 0, stream>>>(hist, bsum, rowptr, NB);
    scatter_convert_kernel<<<2048, 256, 0, stream>>>(
        src, dst, rowptr, cnt, sorted_src, E, bandsL, shift,
        k, v, kvb, use_bf16 ? nodes * 64 : 0);
    if (use_bf16)
        node_kernel_bf16<<<(nodes + 3) / 4, 256, 0, stream>>>(
            q, kvb, rowptr, sorted_src, wv, z, nodes, bandsL, E);
    else
        node_kernel_f32<<<(nodes + 3) / 4, 256, 0, stream>>>(
            q, k, v, rowptr, sorted_src, wv, z, nodes, bandsL, E);
}